// Round 6
// baseline (176.659 us; speedup 1.0000x reference)
//
#include <hip/hip_runtime.h>
#include <hip/hip_bf16.h>

// Renderer vertex-normals rev15. Math FROZEN from rev8 (passing, absmax = 1 bf16 ulp):
//   cross: c_i = fmaf(a_p, b_q, -pinned(a_q*b_p))  (uniform LHS fusion)
//   norms: (x*x + y*y) + z*z, sqrtf, fmaxf(n,1e-12f), IEEE '/'
//   vertex sum: c = 0..5 sequential per (v,batch) accumulator
// Kept: batch-interleaved 64-B ptsI table + quad-split lane mapping (quad's
//   4 lanes share one 64-B entry -> 1 line/quad at the TA), nt streams.
// Rev15 = FUSE face into vertex; eliminate the fn intermediate entirely.
//   Evidence (r14): vertex is traffic-wall-bound (MLP x2 -> no change; 148 MB
//   @ 3.3 TB/s random-line rate). fn accounted for ~160 MB of ~300 MB total
//   (65 write + ~93 read incl. 1.4x refetch: 8.3 MB/XCD slice > 4 MB L2).
//   Fused: each (v,bl) thread recomputes its 6 face normals from ptsI
//   directly (3 corner gathers each). Redundant ~3x compute is ~11 us VALU,
//   hidden under memory. Per-XCD random-gather footprint becomes the 4.19 MB
//   ptsI slice (~ L2 capacity, ~18x reuse -> mostly L2 hits) + 1.56 MB faces
//   table (L2-resident). Read-once vti/vtw/out marked nt to protect L2.
//   Bit-identical: same frozen FP sequence per (face,batch); f32 fn
//   store/load roundtrip was exact; c-order unchanged.
// bs=32, V=65536, F=130050, C=6.

#define XCDS 8
#define BPX  4   // batches per XCD; fast path requires bs == XCDS*BPX == 32

typedef float f32x4 __attribute__((ext_vector_type(4)));
typedef float f32x2 __attribute__((ext_vector_type(2)));
typedef int   i32x2 __attribute__((ext_vector_type(2)));

__device__ __forceinline__ float mulf_pin(float a, float b) {
  float t = a * b;
  asm("" : "+v"(t));   // pin: separately-rounded f32 product, cannot re-fuse
  return t;
}

__device__ __forceinline__ float3 cross_lhs(float ax, float ay, float az,
                                            float bx, float by, float bz) {
  float cx = __builtin_fmaf(ay, bz, -mulf_pin(az, by));
  float cy = __builtin_fmaf(az, bx, -mulf_pin(ax, bz));
  float cz = __builtin_fmaf(ax, by, -mulf_pin(ay, bx));
  return make_float3(cx, cy, cz);
}

// ---------------- Kernel A: batch-interleaved point pack, quad-split -------
// Thread g -> (v = g>>2, bl = g&3). 3 coalesced nt loads, one contiguous
// 16-B/lane store into the XCD's own slice.
__global__ __launch_bounds__(256) void rend15_pack(
    const float* __restrict__ points,   // (bs, 3, V)
    float4*      __restrict__ ptsI,     // (XCDS, V, BPX)
    int V) {
  int xcd = blockIdx.x % XCDS;
  int g   = (blockIdx.x / XCDS) * 256 + threadIdx.x;
  int v   = g >> 2;
  int bl  = g & 3;
  int b   = xcd * BPX + bl;
  const float* pb = points + (size_t)b * 3 * V;
  float x = __builtin_nontemporal_load(pb + v);
  float y = __builtin_nontemporal_load(pb + V + v);
  float z = __builtin_nontemporal_load(pb + 2 * V + v);
  ptsI[((size_t)xcd * V + v) * BPX + bl] = make_float4(x, y, z, 0.0f);
}

// ---------------- Kernel B: FUSED face+vertex normals, quad-split ----------
// Thread (v, bl): 6 nt table loads -> 6 face rows (L2-resident) -> 18
// independent quad-merged 64-B gathers from the XCD's ptsI slice -> 6x frozen
// cross/normalize -> frozen c=0..5 weighted sum -> normalize -> 3 nt stores.
__global__ __launch_bounds__(256) void rend15_fused(
    const float4* __restrict__ ptsI,    // (XCDS, V, BPX)
    const int*    __restrict__ faces,   // (F, 3)
    const int*    __restrict__ vti,     // (V, 6)
    const float*  __restrict__ vtw,     // (V, 6)
    float*        __restrict__ out,     // (bs, V, 3)
    int F, int V) {
  int xcd = blockIdx.x % XCDS;
  int g   = (blockIdx.x / XCDS) * 256 + threadIdx.x;
  int v   = g >> 2;
  int bl  = g & 3;
  if (v >= V) return;

  i32x2 t0 = __builtin_nontemporal_load((const i32x2*)(vti + (size_t)v * 6) + 0);
  i32x2 t1 = __builtin_nontemporal_load((const i32x2*)(vti + (size_t)v * 6) + 1);
  i32x2 t2 = __builtin_nontemporal_load((const i32x2*)(vti + (size_t)v * 6) + 2);
  f32x2 w0 = __builtin_nontemporal_load((const f32x2*)(vtw + (size_t)v * 6) + 0);
  f32x2 w1 = __builtin_nontemporal_load((const f32x2*)(vtw + (size_t)v * 6) + 1);
  f32x2 w2 = __builtin_nontemporal_load((const f32x2*)(vtw + (size_t)v * 6) + 2);

  int   fi[6]  = {t0[0], t0[1], t1[0], t1[1], t2[0], t2[1]};
  float wgt[6] = {w0[0], w0[1], w1[0], w1[1], w2[0], w2[1]};

  // 6 face rows (12 B each; random into a 1.56 MB L2-resident table).
  int ia[6], ib[6], ic[6];
#pragma unroll
  for (int c = 0; c < 6; ++c) {
    ia[c] = faces[3 * fi[c] + 0];
    ib[c] = faces[3 * fi[c] + 1];
    ic[c] = faces[3 * fi[c] + 2];
  }

  // 18 independent quad-merged gathers into the 4.19 MB ptsI slice.
  const float4* P = ptsI + (size_t)xcd * V * BPX;
  float4 p0[6], p1[6], p2[6];
#pragma unroll
  for (int c = 0; c < 6; ++c) {
    p0[c] = P[(size_t)ia[c] * BPX + bl];
    p1[c] = P[(size_t)ib[c] * BPX + bl];
    p2[c] = P[(size_t)ic[c] * BPX + bl];
  }

  // Frozen per-face sequence + frozen c=0..5 accumulation.
  float sx = 0.f, sy = 0.f, sz = 0.f;
#pragma unroll
  for (int c = 0; c < 6; ++c) {
    float ax = p1[c].x - p0[c].x, ay = p1[c].y - p0[c].y, az = p1[c].z - p0[c].z;
    float bx = p2[c].x - p0[c].x, by = p2[c].y - p0[c].y, bz = p2[c].z - p0[c].z;
    float3 cr = cross_lhs(ax, ay, az, bx, by, bz);
    float n = sqrtf((cr.x * cr.x + cr.y * cr.y) + cr.z * cr.z);
    float d = fmaxf(n, 1e-12f);
    float fx = cr.x / d, fy = cr.y / d, fz = cr.z / d;
    sx += fx * wgt[c];
    sy += fy * wgt[c];
    sz += fz * wgt[c];
  }

  float n = sqrtf((sx * sx + sy * sy) + sz * sz);
  float d = fmaxf(n, 1e-12f);

  int b = xcd * BPX + bl;
  size_t o = ((size_t)b * V + v) * 3;
  __builtin_nontemporal_store(sx / d, out + o + 0);
  __builtin_nontemporal_store(sy / d, out + o + 1);
  __builtin_nontemporal_store(sz / d, out + o + 2);
}

// ================= Fallback path (rev8, proven): ===========================
__global__ __launch_bounds__(256) void rend15_face_fb(
    const float* __restrict__ points,
    const int*   __restrict__ faces,
    float4*      __restrict__ fnorm,
    int F, int V) {
  int f = blockIdx.x * blockDim.x + threadIdx.x;
  int b = blockIdx.y;
  if (f >= F) return;

  int i0 = faces[3 * f + 0];
  int i1 = faces[3 * f + 1];
  int i2 = faces[3 * f + 2];

  const float* pb = points + (size_t)b * 3 * V;
  float ax = pb[i1] - pb[i0], ay = pb[V + i1] - pb[V + i0], az = pb[2 * V + i1] - pb[2 * V + i0];
  float bx = pb[i2] - pb[i0], by = pb[V + i2] - pb[V + i0], bz = pb[2 * V + i2] - pb[2 * V + i0];

  float3 c = cross_lhs(ax, ay, az, bx, by, bz);

  float n = sqrtf((c.x * c.x + c.y * c.y) + c.z * c.z);
  float d = fmaxf(n, 1e-12f);

  fnorm[(size_t)b * F + f] = make_float4(c.x / d, c.y / d, c.z / d, 0.0f);
}

__global__ __launch_bounds__(256) void rend15_vertex_fb(
    const float4* __restrict__ fnorm,
    const int*    __restrict__ vti,
    const float*  __restrict__ vtw,
    float*        __restrict__ out,
    int F, int V) {
  int v = blockIdx.x * blockDim.x + threadIdx.x;
  int b = blockIdx.y;
  if (v >= V) return;

  const float4* fb = fnorm + (size_t)b * F;
  float sx = 0.f, sy = 0.f, sz = 0.f;
#pragma unroll
  for (int c = 0; c < 6; ++c) {
    int    idx = vti[v * 6 + c];
    float  w   = vtw[v * 6 + c];
    float4 nr  = fb[idx];
    sx += nr.x * w;
    sy += nr.y * w;
    sz += nr.z * w;
  }
  float n = sqrtf((sx * sx + sy * sy) + sz * sz);
  float d = fmaxf(n, 1e-12f);
  size_t o = ((size_t)b * V + v) * 3;
  out[o + 0] = sx / d;
  out[o + 1] = sy / d;
  out[o + 2] = sz / d;
}

extern "C" void kernel_launch(void* const* d_in, const int* in_sizes, int n_in,
                              void* d_out, int out_size, void* d_ws, size_t ws_size,
                              hipStream_t stream) {
  const float* points = (const float*)d_in[0];
  const int*   faces  = (const int*)d_in[1];
  const int*   vti    = (const int*)d_in[2];
  const float* vtw    = (const float*)d_in[3];
  float*       out    = (float*)d_out;

  const int F  = in_sizes[1] / 3;                       // 130050
  const int V  = in_sizes[2] / 6;                       // 65536
  const int bs = (int)(in_sizes[0] / (3 * (size_t)V));  // 32

  const size_t ptsI_bytes = (size_t)bs * V * sizeof(float4);  // 33.6 MB
  const size_t fn_bytes   = (size_t)bs * F * sizeof(float4);  // 66.6 MB (fallback only)

  const bool fast_ok = (ws_size >= ptsI_bytes) &&
                       (bs == XCDS * BPX) && ((V * BPX) % 256 == 0);

  if (fast_ok) {
    float4* ptsI = (float4*)d_ws;
    const int qpb = (V * BPX) / 256;                // 1024 quad-blocks per XCD

    rend15_pack <<<dim3(XCDS * qpb), dim3(256), 0, stream>>>(points, ptsI, V);
    rend15_fused<<<dim3(XCDS * qpb), dim3(256), 0, stream>>>(
        ptsI, faces, vti, vtw, out, F, V);
  } else if (ws_size >= fn_bytes) {  // rev8 fallback
    float4* fnorm = (float4*)d_ws;
    rend15_face_fb<<<dim3((F + 255) / 256, bs), dim3(256), 0, stream>>>(
        points, faces, fnorm, F, V);
    rend15_vertex_fb<<<dim3((V + 255) / 256, bs), dim3(256), 0, stream>>>(
        fnorm, vti, vtw, out, F, V);
  }
}

// Round 7
// 163.396 us; speedup vs baseline: 1.0812x; 1.0812x over previous
//
#include <hip/hip_runtime.h>
#include <hip/hip_bf16.h>

// Renderer vertex-normals rev16. Math FROZEN from rev8 (passing, absmax = 1 bf16 ulp):
//   cross: c_i = fmaf(a_p, b_q, -pinned(a_q*b_p))  (uniform LHS fusion)
//   norms: (x*x + y*y) + z*z, sqrtf, fmaxf(n,1e-12f), IEEE '/'
//   vertex sum: c = 0..5 sequential per (v,batch) accumulator
// Rev16 = rev13 structure (fusion REVERTED: rev15 fused = 94 us, FETCH 227 MB
//   — 3x redundant gathers thrash L2; materializing fn is cheaper) with
//   PACKED 48-B interleaved entries (w-padding removed, 25% of table bytes):
//     ptsP[xcd][v]  = 4 batches x {x,y,z} f32 = 48 B   (was 64 B float4[4])
//     fnP [xcd][f]  = 4 batches x {x,y,z} f32 = 48 B
//   Evidence: both passes are traffic-proportional (~3 TB/s marginal at every
//   rev; FPT/VPT MLP changes null). ptsP slice 4.19->3.15 MB now FITS the
//   4 MB XCD L2 (face's ~6x reuse fully resident + pack->face carryover);
//   fn traffic 66.6->49.9 MB on both write and read; vertex slice 8.3->6.2.
//   Quad lanes read adjacent 12-B runs -> still one 48-B coalesced segment
//   per quad (dword-aligned multi-dword is legal on gfx950).
//   f32 values identical, store/load roundtrip exact -> bit-identical output.
// Kept: quad-split lane mapping, XCD partitioning, FPT=3 face, VPT=1 vertex,
//   nt streaming loads/stores, frozen FP order.
// bs=32, V=65536, F=130050, C=6.

#define XCDS 8
#define BPX  4   // batches per XCD; fast path requires bs == XCDS*BPX == 32
#define FPT  3   // faces per thread in the face pass (requires F % FPT == 0)

__device__ __forceinline__ float mulf_pin(float a, float b) {
  float t = a * b;
  asm("" : "+v"(t));   // pin: separately-rounded f32 product, cannot re-fuse
  return t;
}

__device__ __forceinline__ float3 cross_lhs(float ax, float ay, float az,
                                            float bx, float by, float bz) {
  float cx = __builtin_fmaf(ay, bz, -mulf_pin(az, by));
  float cy = __builtin_fmaf(az, bx, -mulf_pin(ax, bz));
  float cz = __builtin_fmaf(ax, by, -mulf_pin(ay, bx));
  return make_float3(cx, cy, cz);
}

// ---------------- Kernel A: packed batch-interleaved point pack ------------
// Thread g -> (v = g>>2, bl = g&3). 3 coalesced nt loads; 3 regular stores
// into the XCD's own 3.15 MB slice (stays dirty in L2 for kernel B).
__global__ __launch_bounds__(256) void rend16_pack(
    const float* __restrict__ points,   // (bs, 3, V)
    float*       __restrict__ ptsP,     // (XCDS, V, 12 floats)
    int V) {
  int xcd = blockIdx.x % XCDS;
  int g   = (blockIdx.x / XCDS) * 256 + threadIdx.x;
  int v   = g >> 2;
  int bl  = g & 3;
  int b   = xcd * BPX + bl;
  const float* pb = points + (size_t)b * 3 * V;
  float x = __builtin_nontemporal_load(pb + v);
  float y = __builtin_nontemporal_load(pb + V + v);
  float z = __builtin_nontemporal_load(pb + 2 * V + v);
  float* e = ptsP + ((size_t)xcd * V + v) * 12 + 3 * bl;
  e[0] = x; e[1] = y; e[2] = z;
}

// ---------------- Kernel B: face normals, quad-split, FPT=3, packed --------
// Thread (q, bl) handles f_k = q + k*Q (Q = F/3): 9 index loads, then 9
// independent quad-merged 48-B gathers, then three frozen compute+store
// sequences (12-B nt stores, quad covers 48 B contiguous).
__global__ __launch_bounds__(256) void rend16_face(
    const float* __restrict__ ptsP,     // (XCDS, V, 12 floats)
    const int*   __restrict__ faces,    // (F, 3)
    float*       __restrict__ fnP,      // (XCDS, F, 12 floats)
    int F, int V, int Q) {
  int xcd = blockIdx.x % XCDS;
  int g   = (blockIdx.x / XCDS) * 256 + threadIdx.x;
  int q   = g >> 2;
  int bl  = g & 3;
  if (q >= Q) return;

  int f0 = q;
  int f1 = q + Q;
  int f2 = q + 2 * Q;

  int a0 = __builtin_nontemporal_load(faces + 3 * f0 + 0);
  int a1 = __builtin_nontemporal_load(faces + 3 * f0 + 1);
  int a2 = __builtin_nontemporal_load(faces + 3 * f0 + 2);
  int b0 = __builtin_nontemporal_load(faces + 3 * f1 + 0);
  int b1 = __builtin_nontemporal_load(faces + 3 * f1 + 1);
  int b2 = __builtin_nontemporal_load(faces + 3 * f1 + 2);
  int c0 = __builtin_nontemporal_load(faces + 3 * f2 + 0);
  int c1 = __builtin_nontemporal_load(faces + 3 * f2 + 1);
  int c2 = __builtin_nontemporal_load(faces + 3 * f2 + 2);

  const float* P = ptsP + (size_t)xcd * V * 12 + 3 * bl;
  const float* ea0 = P + (size_t)a0 * 12;
  const float* ea1 = P + (size_t)a1 * 12;
  const float* ea2 = P + (size_t)a2 * 12;
  const float* eb0 = P + (size_t)b0 * 12;
  const float* eb1 = P + (size_t)b1 * 12;
  const float* eb2 = P + (size_t)b2 * 12;
  const float* ec0 = P + (size_t)c0 * 12;
  const float* ec1 = P + (size_t)c1 * 12;
  const float* ec2 = P + (size_t)c2 * 12;

  float a0x = ea0[0], a0y = ea0[1], a0z = ea0[2];
  float a1x = ea1[0], a1y = ea1[1], a1z = ea1[2];
  float a2x = ea2[0], a2y = ea2[1], a2z = ea2[2];
  float b0x = eb0[0], b0y = eb0[1], b0z = eb0[2];
  float b1x = eb1[0], b1y = eb1[1], b1z = eb1[2];
  float b2x = eb2[0], b2y = eb2[1], b2z = eb2[2];
  float c0x = ec0[0], c0y = ec0[1], c0z = ec0[2];
  float c1x = ec1[0], c1y = ec1[1], c1z = ec1[2];
  float c2x = ec2[0], c2y = ec2[1], c2z = ec2[2];

  float* O = fnP + (size_t)xcd * F * 12 + 3 * bl;
  {
    float ax = a1x - a0x, ay = a1y - a0y, az = a1z - a0z;
    float bx = a2x - a0x, by = a2y - a0y, bz = a2z - a0z;
    float3 c = cross_lhs(ax, ay, az, bx, by, bz);
    float n = sqrtf((c.x * c.x + c.y * c.y) + c.z * c.z);
    float d = fmaxf(n, 1e-12f);
    float* o = O + (size_t)f0 * 12;
    __builtin_nontemporal_store(c.x / d, o + 0);
    __builtin_nontemporal_store(c.y / d, o + 1);
    __builtin_nontemporal_store(c.z / d, o + 2);
  }
  {
    float ax = b1x - b0x, ay = b1y - b0y, az = b1z - b0z;
    float bx = b2x - b0x, by = b2y - b0y, bz = b2z - b0z;
    float3 c = cross_lhs(ax, ay, az, bx, by, bz);
    float n = sqrtf((c.x * c.x + c.y * c.y) + c.z * c.z);
    float d = fmaxf(n, 1e-12f);
    float* o = O + (size_t)f1 * 12;
    __builtin_nontemporal_store(c.x / d, o + 0);
    __builtin_nontemporal_store(c.y / d, o + 1);
    __builtin_nontemporal_store(c.z / d, o + 2);
  }
  {
    float ax = c1x - c0x, ay = c1y - c0y, az = c1z - c0z;
    float bx = c2x - c0x, by = c2y - c0y, bz = c2z - c0z;
    float3 c = cross_lhs(ax, ay, az, bx, by, bz);
    float n = sqrtf((c.x * c.x + c.y * c.y) + c.z * c.z);
    float d = fmaxf(n, 1e-12f);
    float* o = O + (size_t)f2 * 12;
    __builtin_nontemporal_store(c.x / d, o + 0);
    __builtin_nontemporal_store(c.y / d, o + 1);
    __builtin_nontemporal_store(c.z / d, o + 2);
  }
}

// ---------------- Kernel C: vertex normals, quad-split, packed -------------
// Thread (v, bl): 6 nt table loads -> 6 independent quad-merged 48-B gathers
// -> frozen c=0..5 weighted sum -> normalize -> 3 nt stores.
__global__ __launch_bounds__(256) void rend16_vertex(
    const float* __restrict__ fnP,      // (XCDS, F, 12 floats)
    const int*   __restrict__ vti,      // (V, 6)
    const float* __restrict__ vtw,      // (V, 6)
    float*       __restrict__ out,      // (bs, V, 3)
    int F, int V) {
  int xcd = blockIdx.x % XCDS;
  int g   = (blockIdx.x / XCDS) * 256 + threadIdx.x;
  int v   = g >> 2;
  int bl  = g & 3;
  if (v >= V) return;

  int i0 = __builtin_nontemporal_load(vti + (size_t)v * 6 + 0);
  int i1 = __builtin_nontemporal_load(vti + (size_t)v * 6 + 1);
  int i2 = __builtin_nontemporal_load(vti + (size_t)v * 6 + 2);
  int i3 = __builtin_nontemporal_load(vti + (size_t)v * 6 + 3);
  int i4 = __builtin_nontemporal_load(vti + (size_t)v * 6 + 4);
  int i5 = __builtin_nontemporal_load(vti + (size_t)v * 6 + 5);
  float w0 = __builtin_nontemporal_load(vtw + (size_t)v * 6 + 0);
  float w1 = __builtin_nontemporal_load(vtw + (size_t)v * 6 + 1);
  float w2 = __builtin_nontemporal_load(vtw + (size_t)v * 6 + 2);
  float w3 = __builtin_nontemporal_load(vtw + (size_t)v * 6 + 3);
  float w4 = __builtin_nontemporal_load(vtw + (size_t)v * 6 + 4);
  float w5 = __builtin_nontemporal_load(vtw + (size_t)v * 6 + 5);

  const float* P = fnP + (size_t)xcd * F * 12 + 3 * bl;
  const float* e0 = P + (size_t)i0 * 12;
  const float* e1 = P + (size_t)i1 * 12;
  const float* e2 = P + (size_t)i2 * 12;
  const float* e3 = P + (size_t)i3 * 12;
  const float* e4 = P + (size_t)i4 * 12;
  const float* e5 = P + (size_t)i5 * 12;

  float n0x = e0[0], n0y = e0[1], n0z = e0[2];
  float n1x = e1[0], n1y = e1[1], n1z = e1[2];
  float n2x = e2[0], n2y = e2[1], n2z = e2[2];
  float n3x = e3[0], n3y = e3[1], n3z = e3[2];
  float n4x = e4[0], n4y = e4[1], n4z = e4[2];
  float n5x = e5[0], n5y = e5[1], n5z = e5[2];

  // Frozen c = 0..5 sequential accumulation.
  float sx = 0.f, sy = 0.f, sz = 0.f;
  sx += n0x * w0; sy += n0y * w0; sz += n0z * w0;
  sx += n1x * w1; sy += n1y * w1; sz += n1z * w1;
  sx += n2x * w2; sy += n2y * w2; sz += n2z * w2;
  sx += n3x * w3; sy += n3y * w3; sz += n3z * w3;
  sx += n4x * w4; sy += n4y * w4; sz += n4z * w4;
  sx += n5x * w5; sy += n5y * w5; sz += n5z * w5;

  float n = sqrtf((sx * sx + sy * sy) + sz * sz);
  float d = fmaxf(n, 1e-12f);

  int b = xcd * BPX + bl;
  size_t o = ((size_t)b * V + v) * 3;
  __builtin_nontemporal_store(sx / d, out + o + 0);
  __builtin_nontemporal_store(sy / d, out + o + 1);
  __builtin_nontemporal_store(sz / d, out + o + 2);
}

// ================= Fallback path (rev8, proven): ===========================
__global__ __launch_bounds__(256) void rend16_face_fb(
    const float* __restrict__ points,
    const int*   __restrict__ faces,
    float4*      __restrict__ fnorm,
    int F, int V) {
  int f = blockIdx.x * blockDim.x + threadIdx.x;
  int b = blockIdx.y;
  if (f >= F) return;

  int i0 = faces[3 * f + 0];
  int i1 = faces[3 * f + 1];
  int i2 = faces[3 * f + 2];

  const float* pb = points + (size_t)b * 3 * V;
  float ax = pb[i1] - pb[i0], ay = pb[V + i1] - pb[V + i0], az = pb[2 * V + i1] - pb[2 * V + i0];
  float bx = pb[i2] - pb[i0], by = pb[V + i2] - pb[V + i0], bz = pb[2 * V + i2] - pb[2 * V + i0];

  float3 c = cross_lhs(ax, ay, az, bx, by, bz);

  float n = sqrtf((c.x * c.x + c.y * c.y) + c.z * c.z);
  float d = fmaxf(n, 1e-12f);

  fnorm[(size_t)b * F + f] = make_float4(c.x / d, c.y / d, c.z / d, 0.0f);
}

__global__ __launch_bounds__(256) void rend16_vertex_fb(
    const float4* __restrict__ fnorm,
    const int*    __restrict__ vti,
    const float*  __restrict__ vtw,
    float*        __restrict__ out,
    int F, int V) {
  int v = blockIdx.x * blockDim.x + threadIdx.x;
  int b = blockIdx.y;
  if (v >= V) return;

  const float4* fb = fnorm + (size_t)b * F;
  float sx = 0.f, sy = 0.f, sz = 0.f;
#pragma unroll
  for (int c = 0; c < 6; ++c) {
    int    idx = vti[v * 6 + c];
    float  w   = vtw[v * 6 + c];
    float4 nr  = fb[idx];
    sx += nr.x * w;
    sy += nr.y * w;
    sz += nr.z * w;
  }
  float n = sqrtf((sx * sx + sy * sy) + sz * sz);
  float d = fmaxf(n, 1e-12f);
  size_t o = ((size_t)b * V + v) * 3;
  out[o + 0] = sx / d;
  out[o + 1] = sy / d;
  out[o + 2] = sz / d;
}

extern "C" void kernel_launch(void* const* d_in, const int* in_sizes, int n_in,
                              void* d_out, int out_size, void* d_ws, size_t ws_size,
                              hipStream_t stream) {
  const float* points = (const float*)d_in[0];
  const int*   faces  = (const int*)d_in[1];
  const int*   vti    = (const int*)d_in[2];
  const float* vtw    = (const float*)d_in[3];
  float*       out    = (float*)d_out;

  const int F  = in_sizes[1] / 3;                       // 130050
  const int V  = in_sizes[2] / 6;                       // 65536
  const int bs = (int)(in_sizes[0] / (3 * (size_t)V));  // 32

  const size_t ptsP_bytes = (size_t)bs * V * 12;        // 25.2 MB (packed)
  const size_t fnP_bytes  = (size_t)bs * F * 12;        // 49.9 MB (packed)
  const size_t fn_bytes   = (size_t)bs * F * sizeof(float4);  // fallback only

  const bool fast_ok = (ws_size >= ptsP_bytes + fnP_bytes) &&
                       (bs == XCDS * BPX) && ((V * BPX) % 256 == 0) &&
                       (F % FPT == 0);

  if (fast_ok) {
    float* ptsP = (float*)d_ws;
    float* fnP  = (float*)((char*)d_ws + ptsP_bytes);
    const int Q   = F / FPT;                        // 43350 face-triples
    const int ppb = (V * BPX) / 256;                // 1024 pack-blocks per XCD
    const int fqb = (Q * 4 + 255) / 256;            // 678 face-quad blocks per XCD
    const int vqb = (V * BPX) / 256;                // 1024 vertex-quad blocks per XCD

    rend16_pack  <<<dim3(XCDS * ppb), dim3(256), 0, stream>>>(points, ptsP, V);
    rend16_face  <<<dim3(XCDS * fqb), dim3(256), 0, stream>>>(ptsP, faces, fnP, F, V, Q);
    rend16_vertex<<<dim3(XCDS * vqb), dim3(256), 0, stream>>>(fnP, vti, vtw, out, F, V);
  } else if (ws_size >= fn_bytes) {  // rev8 fallback
    float4* fnorm = (float4*)d_ws;
    rend16_face_fb<<<dim3((F + 255) / 256, bs), dim3(256), 0, stream>>>(
        points, faces, fnorm, F, V);
    rend16_vertex_fb<<<dim3((V + 255) / 256, bs), dim3(256), 0, stream>>>(
        fnorm, vti, vtw, out, F, V);
  }
}